// Round 4
// baseline (1591.873 us; speedup 1.0000x reference)
//
#include <hip/hip_runtime.h>

// SAGEDense: h=relu(x@W1+b1); hn=mean_agg(h,src,dst); h2=relu(h@Ws+hn@Wn+b); out=relu(h2@W2+b2)
// GEMMs: M=100000, N=K=128, bf16 MFMA fp32-accum.
// Aggregation: bucket-binned edges (64 dst-nodes/bucket, L2-resident write frontier)
// + per-bucket LDS fp32 accumulate. No per-node CSR (fill_adj write-thrash eliminated).

typedef __bf16 bf16x8 __attribute__((ext_vector_type(8)));
typedef float f32x4 __attribute__((ext_vector_type(4)));

#define D 128
#define BKT 64          // dst nodes per bucket
#define SRC_BITS 17     // M=100000 < 2^17; pack = src | (dst_local << 17)

__device__ __forceinline__ unsigned short f2bf(float f){
  unsigned int u = __float_as_uint(f);
  u += 0x7FFF + ((u >> 16) & 1);           // RNE
  return (unsigned short)(u >> 16);
}
__device__ __forceinline__ float bf2f(unsigned int us){
  return __uint_as_float(us << 16);
}

// Transpose+convert one 128x128 fp32 weight (row-major [k][n]) -> bf16 [n][k]
__global__ void prep_w(const float* __restrict__ W, unsigned short* __restrict__ Wt){
  int k = blockIdx.x;
  int n = threadIdx.x;
  Wt[n * D + k] = f2bf(W[k * D + n]);
}

// ---------------- degree + bucket histogram ----------------
__global__ void count_deg(const int* __restrict__ edst, int* __restrict__ cnt, int E){
  int e = blockIdx.x * blockDim.x + threadIdx.x;
  if (e < E) atomicAdd(&cnt[edst[e]], 1);
}

// bcnt[b] = sum of cnt[b*64 .. b*64+64); one wave per bucket
__global__ void bucket_reduce(const int* __restrict__ cnt, int* __restrict__ bcnt,
                              int M, int NB){
  int b = blockIdx.x * 4 + (threadIdx.x >> 6);
  int lane = threadIdx.x & 63;
  if (b >= NB) return;
  int i = b * BKT + lane;
  int v = (i < M) ? cnt[i] : 0;
  #pragma unroll
  for (int d = 32; d > 0; d >>= 1) v += __shfl_down(v, d);
  if (lane == 0) bcnt[b] = v;
}

// ---------------- multi-block exclusive scan (N <= 256*512) ----------------
__global__ void scan_a(const int* __restrict__ in, int* __restrict__ bsum, int N){
  __shared__ int red[256];
  int t = threadIdx.x;
  int i0 = blockIdx.x * 512 + t * 2;
  int s = 0;
  if (i0 < N)     s += in[i0];
  if (i0 + 1 < N) s += in[i0 + 1];
  red[t] = s;
  __syncthreads();
  #pragma unroll
  for (int d = 128; d > 0; d >>= 1){
    if (t < d) red[t] += red[t + d];
    __syncthreads();
  }
  if (t == 0) bsum[blockIdx.x] = red[0];
}

__global__ void scan_b(const int* __restrict__ bsum, int* __restrict__ boff, int nb){
  __shared__ int buf[256];
  int t = threadIdx.x;
  buf[t] = (t < nb) ? bsum[t] : 0;
  __syncthreads();
  #pragma unroll
  for (int d = 1; d < 256; d <<= 1){
    int v = (t >= d) ? buf[t - d] : 0;
    __syncthreads();
    buf[t] += v;
    __syncthreads();
  }
  if (t < nb) boff[t] = (t == 0) ? 0 : buf[t - 1];
}

__global__ void scan_c(const int* __restrict__ in, const int* __restrict__ boff,
                       int* __restrict__ outp, int N){
  __shared__ int buf[256];
  int t = threadIdx.x;
  int i0 = blockIdx.x * 512 + t * 2;
  int c0 = (i0 < N)     ? in[i0]     : 0;
  int c1 = (i0 + 1 < N) ? in[i0 + 1] : 0;
  buf[t] = c0 + c1;
  __syncthreads();
  #pragma unroll
  for (int d = 1; d < 256; d <<= 1){
    int v = (t >= d) ? buf[t - d] : 0;
    __syncthreads();
    buf[t] += v;
    __syncthreads();
  }
  int excl = ((t == 0) ? 0 : buf[t - 1]) + boff[blockIdx.x];
  if (i0 < N)     outp[i0]     = excl;
  if (i0 + 1 < N) outp[i0 + 1] = excl + c0;
  if (i0 + 1 == N - 1) outp[N] = excl + c0 + c1;
  if (i0 == N - 1)     outp[N] = excl + c0;
}

// ---------------- bucket binning ----------------
// Scatter packed (src | dl<<17) into bucket-sorted ebuf. Write frontier =
// NB (~1563) cache lines ~= 100KB -> L2-resident, no HBM write thrash.
__global__ void bin_edges(const int* __restrict__ esrc, const int* __restrict__ edst,
                          const int* __restrict__ bktoff, int* __restrict__ bfill,
                          unsigned* __restrict__ ebuf, int E){
  int e = blockIdx.x * blockDim.x + threadIdx.x;
  if (e >= E) return;
  int s = esrc[e], d = edst[e];
  int b = d >> 6;
  int p = atomicAdd(&bfill[b], 1);
  ebuf[bktoff[b] + p] = (unsigned)s | ((unsigned)(d & (BKT - 1)) << SRC_BITS);
}

// ---------------- per-bucket LDS aggregation ----------------
// One block per bucket. acc[64][128] fp32 in LDS (32KB). Wave-per-edge:
// all 64 lanes share the edge's dl -> acc[dl][lane] is a 2-way bank access (free).
// Lane owns dims (lane, lane+64).
__launch_bounds__(256)
__global__ void agg_bucket(const unsigned short* __restrict__ h,
                           const unsigned* __restrict__ ebuf,
                           const int* __restrict__ bktoff,
                           const int* __restrict__ cnt,
                           unsigned short* __restrict__ hn, int N){
  __shared__ float acc[BKT][D];   // 32KB
  const int t = threadIdx.x;
  const int lane = t & 63;
  const int wave = t >> 6;
  const int b = blockIdx.x;

  #pragma unroll
  for (int i = t; i < BKT * D; i += 256) ((float*)acc)[i] = 0.f;
  __syncthreads();

  const int beg = bktoff[b], end = bktoff[b + 1];
  for (int i = beg + wave; i < end; i += 4){
    unsigned w = ebuf[i];
    int src = w & ((1u << SRC_BITS) - 1);
    int dl  = w >> SRC_BITS;
    const unsigned short* row = h + (size_t)src * D;
    float f0 = bf2f(row[lane]);
    float f1 = bf2f(row[lane + 64]);
    atomicAdd(&acc[dl][lane], f0);
    atomicAdd(&acc[dl][lane + 64], f1);
  }
  __syncthreads();

  // write out: wave handles nodes wave, wave+4, ...; lane packs dims (2l, 2l+1)
  for (int n = wave; n < BKT; n += 4){
    int g = b * BKT + n;
    if (g < N){
      float inv = 1.0f / fmaxf((float)cnt[g], 1.0f);
      unsigned o = (unsigned)f2bf(acc[n][2 * lane] * inv)
                 | ((unsigned)f2bf(acc[n][2 * lane + 1] * inv) << 16);
      *(unsigned*)(hn + (size_t)g * D + 2 * lane) = o;
    }
  }
}

// ---------------- GEMM ----------------
// MODE 0: A1 fp32 -> bf16 out (x@W1)
// MODE 1: A1 bf16 @ Wt1 + A2 bf16 @ Wt2 -> bf16 out (SAGE combine)
// MODE 2: A1 bf16 -> fp32 out (final)
template<int MODE>
__launch_bounds__(256, 2)
__global__ void gemm_k(const void* __restrict__ A1,
                       const unsigned short* __restrict__ Wt1,
                       const void* __restrict__ A2,
                       const unsigned short* __restrict__ Wt2,
                       const float* __restrict__ bias,
                       void* __restrict__ out,
                       int M)
{
  __shared__ unsigned short As[128 * 128];  // [row][k] bf16, XOR-swizzled
  __shared__ unsigned short Bs[128 * 128];  // [n][k]  bf16, XOR-swizzled

  const int t = threadIdx.x;
  const int lane = t & 63;
  const int wave = t >> 6;
  const int rowBase = blockIdx.x * 128;

  f32x4 zero = {0.f, 0.f, 0.f, 0.f};
  f32x4 acc[4][4];
  #pragma unroll
  for (int i = 0; i < 4; i++)
    #pragma unroll
    for (int j = 0; j < 4; j++) acc[i][j] = zero;

  auto stage_bf16 = [&](const unsigned short* A){
    #pragma unroll
    for (int i = 0; i < 8; i++){
      int idx = t + i * 256;
      int row = idx >> 4;
      int inb = (idx & 15) << 4;
      int g = rowBase + row; if (g >= M) g = M - 1;
      uint4 v = *(const uint4*)((const char*)A + (size_t)g * 256 + inb);
      *(uint4*)((char*)As + row * 256 + (inb ^ ((row & 7) << 4))) = v;
    }
  };
  auto stage_f32 = [&](const float* A){
    #pragma unroll
    for (int i = 0; i < 8; i++){
      int idx = t + i * 256;
      int row = idx >> 4;
      int inb = (idx & 15) << 4;
      int g = rowBase + row; if (g >= M) g = M - 1;
      const float* src = A + (size_t)g * D + (inb >> 1);
      float4 v0 = *(const float4*)src;
      float4 v1 = *(const float4*)(src + 4);
      uint4 o;
      o.x = (unsigned)f2bf(v0.x) | ((unsigned)f2bf(v0.y) << 16);
      o.y = (unsigned)f2bf(v0.z) | ((unsigned)f2bf(v0.w) << 16);
      o.z = (unsigned)f2bf(v1.x) | ((unsigned)f2bf(v1.y) << 16);
      o.w = (unsigned)f2bf(v1.z) | ((unsigned)f2bf(v1.w) << 16);
      *(uint4*)((char*)As + row * 256 + (inb ^ ((row & 7) << 4))) = o;
    }
  };
  auto stage_w = [&](const unsigned short* W){
    #pragma unroll
    for (int i = 0; i < 8; i++){
      int idx = t + i * 256;
      int row = idx >> 4;
      int inb = (idx & 15) << 4;
      uint4 v = *(const uint4*)((const char*)W + row * 256 + inb);
      *(uint4*)((char*)Bs + row * 256 + (inb ^ ((row & 7) << 4))) = v;
    }
  };

  const int wr = (wave >> 1) * 64;
  const int wc = (wave & 1) * 64;
  const int fr = lane & 15;
  const int kg = lane >> 4;

  auto ld_frag = [&](const unsigned short* S, int row, int kb) -> bf16x8 {
    uint4 v = *(const uint4*)((const char*)S + row * 256 + (kb ^ ((row & 7) << 4)));
    return __builtin_bit_cast(bf16x8, v);
  };
  auto mma_pass = [&](){
    #pragma unroll
    for (int ks = 0; ks < 4; ks++){
      int kb = ks * 64 + kg * 16;
      bf16x8 a[4], b[4];
      #pragma unroll
      for (int mi = 0; mi < 4; mi++) a[mi] = ld_frag(As, wr + mi * 16 + fr, kb);
      #pragma unroll
      for (int ni = 0; ni < 4; ni++) b[ni] = ld_frag(Bs, wc + ni * 16 + fr, kb);
      #pragma unroll
      for (int mi = 0; mi < 4; mi++)
        #pragma unroll
        for (int ni = 0; ni < 4; ni++)
          acc[mi][ni] = __builtin_amdgcn_mfma_f32_16x16x32_bf16(a[mi], b[ni], acc[mi][ni], 0, 0, 0);
    }
  };

  if (MODE == 0){
    stage_f32((const float*)A1);
    stage_w(Wt1);
    __syncthreads();
    mma_pass();
  } else if (MODE == 1){
    stage_bf16((const unsigned short*)A1);
    stage_w(Wt1);
    __syncthreads();
    mma_pass();
    __syncthreads();
    stage_bf16((const unsigned short*)A2);
    stage_w(Wt2);
    __syncthreads();
    mma_pass();
  } else {
    stage_bf16((const unsigned short*)A1);
    stage_w(Wt1);
    __syncthreads();
    mma_pass();
  }

  // epilogue: bias + relu. C/D layout: col=lane&15, row=(lane>>4)*4+reg
  #pragma unroll
  for (int ni = 0; ni < 4; ni++){
    int col = wc + ni * 16 + fr;
    float bv = bias[col];
    #pragma unroll
    for (int mi = 0; mi < 4; mi++){
      #pragma unroll
      for (int j = 0; j < 4; j++){
        int row = rowBase + wr + mi * 16 + kg * 4 + j;
        if (row < M){
          float v = fmaxf(acc[mi][ni][j] + bv, 0.0f);
          if (MODE == 2) ((float*)out)[(size_t)row * D + col] = v;
          else ((unsigned short*)out)[(size_t)row * D + col] = f2bf(v);
        }
      }
    }
  }
}

extern "C" void kernel_launch(void* const* d_in, const int* in_sizes, int n_in,
                              void* d_out, int out_size, void* d_ws, size_t ws_size,
                              hipStream_t stream)
{
  const float* x     = (const float*)d_in[0];
  const int*   esrc  = (const int*)d_in[1];
  const int*   edst  = (const int*)d_in[2];
  const float* W1    = (const float*)d_in[3];
  const float* b1    = (const float*)d_in[4];
  const float* Wself = (const float*)d_in[5];
  const float* Wneigh= (const float*)d_in[6];
  const float* bsage = (const float*)d_in[7];
  const float* W2    = (const float*)d_in[8];
  const float* b2    = (const float*)d_in[9];

  const int M = in_sizes[0] / D;   // 100000
  const int E = in_sizes[1];       // 1600000
  const int NB = (M + BKT - 1) / BKT;   // 1563 buckets

  // ---- workspace layout ----
  char* ws = (char*)d_ws;
  unsigned short* W1t = (unsigned short*)(ws);
  unsigned short* Wst = (unsigned short*)(ws + 32768);
  unsigned short* Wnt = (unsigned short*)(ws + 65536);
  unsigned short* W2t = (unsigned short*)(ws + 98304);
  size_t hbytes = (size_t)M * D * 2;            // 25.6 MB each
  unsigned short* h   = (unsigned short*)(ws + 131072);
  unsigned short* h2  = (unsigned short*)(ws + 131072 + hbytes);
  unsigned short* hn  = (unsigned short*)(ws + 131072 + 2 * hbytes);
  char* p = ws + 131072 + 3 * hbytes;
  int* cnt    = (int*)p;                 p += (size_t)M * 4;
  int* bcnt   = (int*)p;                 p += 8192;
  int* bktoff = (int*)p;                 p += 8192;   // NB+1 ints
  int* bfill  = (int*)p;                 p += 8192;
  int* sSum   = (int*)p;                 p += 1024;
  int* sOff   = (int*)p;                 p += 1024;
  unsigned* ebuf = (unsigned*)p;         // E * 4 = 6.4 MB

  prep_w<<<D, D, 0, stream>>>(W1, W1t);
  prep_w<<<D, D, 0, stream>>>(Wself, Wst);
  prep_w<<<D, D, 0, stream>>>(Wneigh, Wnt);
  prep_w<<<D, D, 0, stream>>>(W2, W2t);

  hipMemsetAsync(cnt, 0, (size_t)M * 4, stream);
  hipMemsetAsync(bfill, 0, (size_t)NB * 4, stream);

  int nblk = (M + 127) / 128;

  // h = relu(x @ W1 + b1)
  gemm_k<0><<<nblk, 256, 0, stream>>>(x, W1t, nullptr, nullptr, b1, h, M);

  // degree + bucket histogram + bucket offsets
  count_deg<<<(E + 255) / 256, 256, 0, stream>>>(edst, cnt, E);
  bucket_reduce<<<(NB + 3) / 4, 256, 0, stream>>>(cnt, bcnt, M, NB);
  const int nbScan = (NB + 511) / 512;   // 4
  scan_a<<<nbScan, 256, 0, stream>>>(bcnt, sSum, NB);
  scan_b<<<1, 256, 0, stream>>>(sSum, sOff, nbScan);
  scan_c<<<nbScan, 256, 0, stream>>>(bcnt, sOff, bktoff, NB);

  // bucket-sorted packed edges
  bin_edges<<<(E + 255) / 256, 256, 0, stream>>>(esrc, edst, bktoff, bfill, ebuf, E);

  // hn = mean over neighbors (bf16), per-bucket LDS accumulate
  agg_bucket<<<NB, 256, 0, stream>>>(h, ebuf, bktoff, cnt, hn, M);

  // h2 = relu(h @ W_self + hn @ W_neigh + b_sage)
  gemm_k<1><<<nblk, 256, 0, stream>>>(h, Wst, hn, Wnt, bsage, h2, M);

  // out = relu(h2 @ W2 + b2)
  gemm_k<2><<<nblk, 256, 0, stream>>>(h2, W2t, nullptr, nullptr, b2, d_out, M);
}

// Round 5
// 318.366 us; speedup vs baseline: 5.0001x; 5.0001x over previous
//
#include <hip/hip_runtime.h>

// SAGEDense: h=relu(x@W1+b1); hn=mean_agg(h,src,dst); h2=relu(h@Ws+hn@Wn+b); out=relu(h2@W2+b2)
// GEMMs: M=100000, N=K=128, bf16 MFMA fp32-accum.
// Aggregation: CSR (count / multiblock scan / XCD-partitioned fill) + per-node
// register-accumulating gather (round-3 proven). Round-4 LDS-atomic agg reverted.

typedef __bf16 bf16x8 __attribute__((ext_vector_type(8)));
typedef float f32x4 __attribute__((ext_vector_type(4)));

#define D 128

__device__ __forceinline__ unsigned short f2bf(float f){
  unsigned int u = __float_as_uint(f);
  u += 0x7FFF + ((u >> 16) & 1);           // RNE
  return (unsigned short)(u >> 16);
}
__device__ __forceinline__ float bf2f(unsigned int us){
  return __uint_as_float(us << 16);
}

// All 4 weights in one launch: 512 blocks = 4 x 128 k-rows; [k][n] fp32 -> [n][k] bf16
__global__ void prep_w_all(const float* __restrict__ Wa, const float* __restrict__ Wb,
                           const float* __restrict__ Wc, const float* __restrict__ Wd,
                           unsigned short* __restrict__ Ta, unsigned short* __restrict__ Tb,
                           unsigned short* __restrict__ Tc, unsigned short* __restrict__ Td){
  int which = blockIdx.x >> 7;
  int k = blockIdx.x & 127;
  int n = threadIdx.x;
  const float* W = (which == 0) ? Wa : (which == 1) ? Wb : (which == 2) ? Wc : Wd;
  unsigned short* T = (which == 0) ? Ta : (which == 1) ? Tb : (which == 2) ? Tc : Td;
  T[n * D + k] = f2bf(W[k * D + n]);
}

// ---------------- CSR build ----------------
__global__ void count_deg(const int* __restrict__ edst, int* __restrict__ cnt, int E){
  int e = blockIdx.x * blockDim.x + threadIdx.x;
  if (e < E) atomicAdd(&cnt[edst[e]], 1);
}

// Multi-block exclusive scan of cnt[0..N) -> rowptr[0..N] (and fillpos copy).
__global__ void scan_a(const int* __restrict__ in, int* __restrict__ bsum, int N){
  __shared__ int red[256];
  int t = threadIdx.x;
  int i0 = blockIdx.x * 512 + t * 2;
  int s = 0;
  if (i0 < N)     s += in[i0];
  if (i0 + 1 < N) s += in[i0 + 1];
  red[t] = s;
  __syncthreads();
  #pragma unroll
  for (int d = 128; d > 0; d >>= 1){
    if (t < d) red[t] += red[t + d];
    __syncthreads();
  }
  if (t == 0) bsum[blockIdx.x] = red[0];
}

__global__ void scan_b(const int* __restrict__ bsum, int* __restrict__ boff, int nb){
  __shared__ int buf[256];
  int t = threadIdx.x;
  buf[t] = (t < nb) ? bsum[t] : 0;
  __syncthreads();
  #pragma unroll
  for (int d = 1; d < 256; d <<= 1){
    int v = (t >= d) ? buf[t - d] : 0;
    __syncthreads();
    buf[t] += v;
    __syncthreads();
  }
  if (t < nb) boff[t] = (t == 0) ? 0 : buf[t - 1];
}

__global__ void scan_c(const int* __restrict__ in, const int* __restrict__ boff,
                       int* __restrict__ rowptr, int* __restrict__ fillpos, int N){
  __shared__ int buf[256];
  int t = threadIdx.x;
  int i0 = blockIdx.x * 512 + t * 2;
  int c0 = (i0 < N)     ? in[i0]     : 0;
  int c1 = (i0 + 1 < N) ? in[i0 + 1] : 0;
  buf[t] = c0 + c1;
  __syncthreads();
  #pragma unroll
  for (int d = 1; d < 256; d <<= 1){
    int v = (t >= d) ? buf[t - d] : 0;
    __syncthreads();
    buf[t] += v;
    __syncthreads();
  }
  int excl = ((t == 0) ? 0 : buf[t - 1]) + boff[blockIdx.x];
  if (i0 < N)    { rowptr[i0]     = excl;      fillpos[i0]     = excl; }
  if (i0 + 1 < N){ rowptr[i0 + 1] = excl + c0; fillpos[i0 + 1] = excl + c0; }
  if (i0 + 1 == N - 1) rowptr[N] = excl + c0 + c1;
  if (i0 == N - 1)     rowptr[N] = excl + c0;
}

// XCD-partitioned fill: blockIdx%8 selects a dst-range (heuristically one XCD
// via round-robin dispatch) so each adj/fillpos line has a single writing XCD
// -> writes merge in that XCD's L2 (write frontier 800KB << 4MB).
// Cost: edges re-read 8x (coalesced, ~100MB total). fillpos pre-seeded = rowptr.
__global__ void fill_adj_xcd(const int* __restrict__ esrc, const int* __restrict__ edst,
                             int* __restrict__ fillpos, int* __restrict__ adj,
                             int E, int M){
  const int xcd = blockIdx.x & 7;
  const int chunk = blockIdx.x >> 3;
  const int lo = (int)(((long long)M * xcd) >> 3);
  const int hi = (int)(((long long)M * (xcd + 1)) >> 3);
  const int base = chunk * 2048;
  const int lim = min(base + 2048, E);
  for (int i = base + threadIdx.x; i < lim; i += 256){
    int d = edst[i];
    if (d >= lo && d < hi){
      int p = atomicAdd(&fillpos[d], 1);
      adj[p] = esrc[i];
    }
  }
}

// one wave per dst node; lane owns 4 bytes (2 bf16 dims); fp32 register accumulate
__global__ void gather_mean(const unsigned short* __restrict__ h,
                            const int* __restrict__ rowptr,
                            const int* __restrict__ adj,
                            unsigned short* __restrict__ hn, int N){
  int wid = (blockIdx.x * blockDim.x + threadIdx.x) >> 6;
  int lane = threadIdx.x & 63;
  if (wid >= N) return;
  int beg = rowptr[wid], end = rowptr[wid + 1];
  float a0 = 0.f, a1 = 0.f;
  int i = beg;
  for (; i + 3 < end; i += 4){
    int s0 = adj[i], s1 = adj[i + 1], s2 = adj[i + 2], s3 = adj[i + 3];
    unsigned p0 = *(const unsigned*)(h + (size_t)s0 * D + lane * 2);
    unsigned p1 = *(const unsigned*)(h + (size_t)s1 * D + lane * 2);
    unsigned p2 = *(const unsigned*)(h + (size_t)s2 * D + lane * 2);
    unsigned p3 = *(const unsigned*)(h + (size_t)s3 * D + lane * 2);
    a0 += bf2f(p0 & 0xffffu); a1 += bf2f(p0 >> 16);
    a0 += bf2f(p1 & 0xffffu); a1 += bf2f(p1 >> 16);
    a0 += bf2f(p2 & 0xffffu); a1 += bf2f(p2 >> 16);
    a0 += bf2f(p3 & 0xffffu); a1 += bf2f(p3 >> 16);
  }
  for (; i < end; i++){
    int s0 = adj[i];
    unsigned p0 = *(const unsigned*)(h + (size_t)s0 * D + lane * 2);
    a0 += bf2f(p0 & 0xffffu); a1 += bf2f(p0 >> 16);
  }
  float inv = 1.0f / fmaxf((float)(end - beg), 1.0f);
  unsigned o = (unsigned)f2bf(a0 * inv) | ((unsigned)f2bf(a1 * inv) << 16);
  *(unsigned*)(hn + (size_t)wid * D + lane * 2) = o;
}

// ---------------- GEMM ----------------
// MODE 0: A1 fp32 -> bf16 out (x@W1)
// MODE 1: A1 bf16 @ Wt1 + A2 bf16 @ Wt2 -> bf16 out (SAGE combine)
// MODE 2: A1 bf16 -> fp32 out (final)
template<int MODE>
__launch_bounds__(256, 2)
__global__ void gemm_k(const void* __restrict__ A1,
                       const unsigned short* __restrict__ Wt1,
                       const void* __restrict__ A2,
                       const unsigned short* __restrict__ Wt2,
                       const float* __restrict__ bias,
                       void* __restrict__ out,
                       int M)
{
  __shared__ unsigned short As[128 * 128];  // [row][k] bf16, XOR-swizzled
  __shared__ unsigned short Bs[128 * 128];  // [n][k]  bf16, XOR-swizzled

  const int t = threadIdx.x;
  const int lane = t & 63;
  const int wave = t >> 6;
  const int rowBase = blockIdx.x * 128;

  f32x4 zero = {0.f, 0.f, 0.f, 0.f};
  f32x4 acc[4][4];
  #pragma unroll
  for (int i = 0; i < 4; i++)
    #pragma unroll
    for (int j = 0; j < 4; j++) acc[i][j] = zero;

  auto stage_bf16 = [&](const unsigned short* A){
    #pragma unroll
    for (int i = 0; i < 8; i++){
      int idx = t + i * 256;
      int row = idx >> 4;
      int inb = (idx & 15) << 4;
      int g = rowBase + row; if (g >= M) g = M - 1;
      uint4 v = *(const uint4*)((const char*)A + (size_t)g * 256 + inb);
      *(uint4*)((char*)As + row * 256 + (inb ^ ((row & 7) << 4))) = v;
    }
  };
  auto stage_f32 = [&](const float* A){
    #pragma unroll
    for (int i = 0; i < 8; i++){
      int idx = t + i * 256;
      int row = idx >> 4;
      int inb = (idx & 15) << 4;
      int g = rowBase + row; if (g >= M) g = M - 1;
      const float* src = A + (size_t)g * D + (inb >> 1);
      float4 v0 = *(const float4*)src;
      float4 v1 = *(const float4*)(src + 4);
      uint4 o;
      o.x = (unsigned)f2bf(v0.x) | ((unsigned)f2bf(v0.y) << 16);
      o.y = (unsigned)f2bf(v0.z) | ((unsigned)f2bf(v0.w) << 16);
      o.z = (unsigned)f2bf(v1.x) | ((unsigned)f2bf(v1.y) << 16);
      o.w = (unsigned)f2bf(v1.z) | ((unsigned)f2bf(v1.w) << 16);
      *(uint4*)((char*)As + row * 256 + (inb ^ ((row & 7) << 4))) = o;
    }
  };
  auto stage_w = [&](const unsigned short* W){
    #pragma unroll
    for (int i = 0; i < 8; i++){
      int idx = t + i * 256;
      int row = idx >> 4;
      int inb = (idx & 15) << 4;
      uint4 v = *(const uint4*)((const char*)W + row * 256 + inb);
      *(uint4*)((char*)Bs + row * 256 + (inb ^ ((row & 7) << 4))) = v;
    }
  };

  const int wr = (wave >> 1) * 64;
  const int wc = (wave & 1) * 64;
  const int fr = lane & 15;
  const int kg = lane >> 4;

  auto ld_frag = [&](const unsigned short* S, int row, int kb) -> bf16x8 {
    uint4 v = *(const uint4*)((const char*)S + row * 256 + (kb ^ ((row & 7) << 4)));
    return __builtin_bit_cast(bf16x8, v);
  };
  auto mma_pass = [&](){
    #pragma unroll
    for (int ks = 0; ks < 4; ks++){
      int kb = ks * 64 + kg * 16;
      bf16x8 a[4], b[4];
      #pragma unroll
      for (int mi = 0; mi < 4; mi++) a[mi] = ld_frag(As, wr + mi * 16 + fr, kb);
      #pragma unroll
      for (int ni = 0; ni < 4; ni++) b[ni] = ld_frag(Bs, wc + ni * 16 + fr, kb);
      #pragma unroll
      for (int mi = 0; mi < 4; mi++)
        #pragma unroll
        for (int ni = 0; ni < 4; ni++)
          acc[mi][ni] = __builtin_amdgcn_mfma_f32_16x16x32_bf16(a[mi], b[ni], acc[mi][ni], 0, 0, 0);
    }
  };

  if (MODE == 0){
    stage_f32((const float*)A1);
    stage_w(Wt1);
    __syncthreads();
    mma_pass();
  } else if (MODE == 1){
    stage_bf16((const unsigned short*)A1);
    stage_w(Wt1);
    __syncthreads();
    mma_pass();
    __syncthreads();
    stage_bf16((const unsigned short*)A2);
    stage_w(Wt2);
    __syncthreads();
    mma_pass();
  } else {
    stage_bf16((const unsigned short*)A1);
    stage_w(Wt1);
    __syncthreads();
    mma_pass();
  }

  // epilogue: bias + relu. C/D layout: col=lane&15, row=(lane>>4)*4+reg
  #pragma unroll
  for (int ni = 0; ni < 4; ni++){
    int col = wc + ni * 16 + fr;
    float bv = bias[col];
    #pragma unroll
    for (int mi = 0; mi < 4; mi++){
      #pragma unroll
      for (int j = 0; j < 4; j++){
        int row = rowBase + wr + mi * 16 + kg * 4 + j;
        if (row < M){
          float v = fmaxf(acc[mi][ni][j] + bv, 0.0f);
          if (MODE == 2) ((float*)out)[(size_t)row * D + col] = v;
          else ((unsigned short*)out)[(size_t)row * D + col] = f2bf(v);
        }
      }
    }
  }
}

extern "C" void kernel_launch(void* const* d_in, const int* in_sizes, int n_in,
                              void* d_out, int out_size, void* d_ws, size_t ws_size,
                              hipStream_t stream)
{
  const float* x     = (const float*)d_in[0];
  const int*   esrc  = (const int*)d_in[1];
  const int*   edst  = (const int*)d_in[2];
  const float* W1    = (const float*)d_in[3];
  const float* b1    = (const float*)d_in[4];
  const float* Wself = (const float*)d_in[5];
  const float* Wneigh= (const float*)d_in[6];
  const float* bsage = (const float*)d_in[7];
  const float* W2    = (const float*)d_in[8];
  const float* b2    = (const float*)d_in[9];

  const int M = in_sizes[0] / D;   // 100000
  const int E = in_sizes[1];       // 1600000

  // ---- workspace layout ----
  char* ws = (char*)d_ws;
  unsigned short* W1t = (unsigned short*)(ws);
  unsigned short* Wst = (unsigned short*)(ws + 32768);
  unsigned short* Wnt = (unsigned short*)(ws + 65536);
  unsigned short* W2t = (unsigned short*)(ws + 98304);
  size_t hbytes = (size_t)M * D * 2;            // 25.6 MB each
  unsigned short* h   = (unsigned short*)(ws + 131072);
  unsigned short* h2  = (unsigned short*)(ws + 131072 + hbytes);
  unsigned short* hn  = (unsigned short*)(ws + 131072 + 2 * hbytes);
  char* p = ws + 131072 + 3 * hbytes;
  int* cnt     = (int*)p;                 p += (size_t)M * 4;
  int* fillpos = (int*)p;                 p += (size_t)M * 4;
  int* rowptr  = (int*)p;                 p += (size_t)(M + 4) * 4;
  int* bsum    = (int*)p;                 p += 1024;
  int* boff    = (int*)p;                 p += 1024;
  int* adj     = (int*)p;                 // E * 4 = 6.4 MB

  const int nbScan = (M + 511) / 512;     // 196 <= 256

  prep_w_all<<<4 * D, D, 0, stream>>>(W1, Wself, Wneigh, W2, W1t, Wst, Wnt, W2t);

  hipMemsetAsync(cnt, 0, (size_t)M * 4, stream);

  int nblk = (M + 127) / 128;

  // h = relu(x @ W1 + b1)
  gemm_k<0><<<nblk, 256, 0, stream>>>(x, W1t, nullptr, nullptr, b1, h, M);

  // CSR build
  count_deg<<<(E + 255) / 256, 256, 0, stream>>>(edst, cnt, E);
  scan_a<<<nbScan, 256, 0, stream>>>(cnt, bsum, M);
  scan_b<<<1, 256, 0, stream>>>(bsum, boff, nbScan);
  scan_c<<<nbScan, 256, 0, stream>>>(cnt, boff, rowptr, fillpos, M);
  {
    int chunks = (E + 2047) / 2048;
    fill_adj_xcd<<<8 * chunks, 256, 0, stream>>>(esrc, edst, fillpos, adj, E, M);
  }

  // hn = mean over neighbors (bf16)
  gather_mean<<<(M * 64 + 255) / 256, 256, 0, stream>>>(h, rowptr, adj, hn, M);

  // h2 = relu(h @ W_self + hn @ W_neigh + b_sage)
  gemm_k<1><<<nblk, 256, 0, stream>>>(h, Wst, hn, Wnt, bsage, h2, M);

  // out = relu(h2 @ W2 + b2)
  gemm_k<2><<<nblk, 256, 0, stream>>>(h2, W2t, nullptr, nullptr, b2, d_out, M);
}